// Round 15
// baseline (466.908 us; speedup 1.0000x reference)
//
#include <hip/hip_runtime.h>

#define NN 2048          // nodes
#define MD 1024          // mem/input dim
#define NOUT 4096        // 3M (iou) + M (f) output columns
#define GBLK 256         // cooperative grid blocks: one 4-col strip each
#define GTHR 512         // threads per block (8 waves); LDS-bound 1 blk/CU -> VGPR free to 256
#define CAP 1024         // max level width held in LDS (spill to global beyond)

typedef __attribute__((ext_vector_type(8))) short short8;   // 8 x bf16 fragment
typedef __attribute__((ext_vector_type(4))) float f4;

__device__ __forceinline__ unsigned short f2bf(float f) {
  unsigned u = __float_as_uint(f);
  u += 0x7fffu + ((u >> 16) & 1u);      // RNE
  return (unsigned short)(u >> 16);
}
__device__ __forceinline__ uint4 pack8(f4 a, f4 b) {
  uint4 r;
  r.x = f2bf(a[0]) | ((unsigned)f2bf(a[1]) << 16);
  r.y = f2bf(a[2]) | ((unsigned)f2bf(a[3]) << 16);
  r.z = f2bf(b[0]) | ((unsigned)f2bf(b[1]) << 16);
  r.w = f2bf(b[2]) | ((unsigned)f2bf(b[3]) << 16);
  return r;
}
__device__ __forceinline__ float blo(unsigned u) { return __uint_as_float(u << 16); }
__device__ __forceinline__ float bhi(unsigned u) { return __uint_as_float(u & 0xffff0000u); }
__device__ __forceinline__ float sigm(float x) { return 1.0f / (1.0f + __expf(-x)); }
__device__ __forceinline__ float tanh_(float x) { return 1.0f - 2.0f / (1.0f + __expf(2.0f * x)); }

// ---------------- fused cvt + prep kernel (1024 threads) ----------------
// Block 0: full prep (depth, parent-sort, BFS order, biasC, flag reset).
// Blocks 1..: grid-stride fp32->bf16 of X, Wioux, Wfx.
__global__ __launch_bounds__(1024) void cvt_prep_kernel(const float* __restrict__ X,
                                                        const float* __restrict__ Wioux,
                                                        const float* __restrict__ Wfx,
                                                        unsigned short* __restrict__ Xb,
                                                        unsigned short* __restrict__ Wpre,
                                                        const int* __restrict__ parent,
                                                        int2* __restrict__ meta,
                                                        int* __restrict__ doff_g,
                                                        int* __restrict__ maxd_out,
                                                        int* __restrict__ flags,
                                                        const float* __restrict__ bioux,
                                                        const float* __restrict__ biouh,
                                                        const float* __restrict__ bfx,
                                                        const float* __restrict__ bfh,
                                                        float* __restrict__ biasC) {
  __shared__ int s_anc[NN], s_dep[NN];
  __shared__ int s_t1[NN + 2], s_t2[NN + 2];
  __shared__ int s_poff[NN + 2], s_cur[NN + 2];
  __shared__ int s_ordp[NN], s_nord[NN];
  __shared__ int s_doff[NN + 2];
  __shared__ int s_sc[NN], s_sc2[NN];
  __shared__ int s_wsum[17];
  __shared__ int s_maxd;
  const int tid = threadIdx.x;

  if (blockIdx.x != 0) {                 // ---------- cvt part ----------
    const int nX = NN * MD / 4;
    const int nWi = 3072 * MD / 4;
    const int nWf = 1024 * MD / 4;
    int i = (blockIdx.x - 1) * 1024 + tid;
    const float* s; unsigned short* d; int off;
    if (i < nX) { s = X; d = Xb; off = i; }
    else if (i < nX + nWi) { s = Wioux; d = Wpre; off = i - nX; }
    else if (i < nX + nWi + nWf) { s = Wfx; d = Wpre + (size_t)3072 * MD; off = i - nX - nWi; }
    else return;
    f4 v = *((const f4*)s + off);
    uint2 r;
    r.x = f2bf(v[0]) | ((unsigned)f2bf(v[1]) << 16);
    r.y = f2bf(v[2]) | ((unsigned)f2bf(v[3]) << 16);
    *((uint2*)d + off) = r;
    return;
  }

  // ---------- prep part (block 0 only) ----------
  if (tid == 0) s_maxd = 0;
  for (int i = tid; i < GBLK + 64; i += 1024) flags[i] = 0;   // reset barrier epochs
  for (int i = tid; i < NOUT; i += 1024)                       // combined bias
    biasC[i] = (i < 3072) ? (bioux[i] + biouh[i]) : (bfx[i - 3072] + bfh[i - 3072]);
  for (int t = tid; t < NN; t += 1024) {
    bool root = (t == NN - 1);
    s_anc[t] = root ? t : parent[t];
    s_dep[t] = root ? 0 : 1;
  }
  __syncthreads();
  for (int it = 0; it < 11; ++it) {     // 2^11 >= NN
    for (int t = tid; t < NN; t += 1024) { int a = s_anc[t]; s_t1[t] = s_dep[t] + s_dep[a]; s_t2[t] = s_anc[a]; }
    __syncthreads();
    for (int t = tid; t < NN; t += 1024) { s_dep[t] = s_t1[t]; s_anc[t] = s_t2[t]; }
    __syncthreads();
  }
  for (int t = tid; t < NN; t += 1024) atomicMax(&s_maxd, s_dep[t]);

  // ---- counting sort by parent -> s_ordp with offsets s_poff ----
  for (int i = tid; i < NN + 2; i += 1024) s_t2[i] = 0;
  __syncthreads();
  for (int t = tid; t < NN; t += 1024) atomicAdd(&s_t2[parent[t]], 1);
  __syncthreads();
  {
    const int L = NN + 2;
    int* src = s_t2; int* dst = s_t1;
    for (int o = 1; o < L; o <<= 1) {
      for (int i = tid; i < L; i += 1024) dst[i] = src[i] + ((i >= o) ? src[i - o] : 0);
      __syncthreads();
      int* tmp = src; src = dst; dst = tmp;
    }
    for (int i = tid; i < L; i += 1024) { int v = (i ? src[i - 1] : 0); s_poff[i] = v; s_cur[i] = v; }
    __syncthreads();
    for (int t = tid; t < NN; t += 1024) {
      int pos = atomicAdd(&s_cur[parent[t]], 1);
      s_ordp[pos] = t;
    }
    __syncthreads();
    for (int p = tid; p < NN + 1; p += 1024) {    // determinism within bucket
      int b = s_poff[p], e = s_poff[p + 1];
      for (int i = b + 1; i < e; ++i) {
        int v = s_ordp[i], j = i - 1;
        while (j >= b && s_ordp[j] > v) { s_ordp[j + 1] = s_ordp[j]; --j; }
        s_ordp[j + 1] = v;
      }
    }
    __syncthreads();
  }

  // ---- counts by depth -> s_doff ----
  for (int i = tid; i < NN + 2; i += 1024) s_t2[i] = 0;
  __syncthreads();
  for (int t = tid; t < NN; t += 1024) atomicAdd(&s_t2[s_dep[t]], 1);
  __syncthreads();
  {
    const int L = NN + 1;
    int* src = s_t2; int* dst = s_t1;
    for (int o = 1; o < L; o <<= 1) {
      for (int i = tid; i < L; i += 1024) dst[i] = src[i] + ((i >= o) ? src[i - o] : 0);
      __syncthreads();
      int* tmp = src; src = dst; dst = tmp;
    }
    for (int i = tid; i < L + 1; i += 1024) s_doff[i] = (i ? src[i - 1] : 0);
    __syncthreads();
  }

  // ---- BFS: parent-grouped order per level; child indices level-relative ----
  const int maxd = s_maxd;
  if (tid == 0) s_nord[0] = NN - 1;     // root at position 0
  __syncthreads();
  for (int d = 0; d < maxd; ++d) {
    const int lbeg = s_doff[d], lend = s_doff[d + 1];
    const int nd = lend - lbeg;
    if (nd <= 1024) {
      int t = -1, v = 0;
      if (tid < nd) { t = s_nord[lbeg + tid]; v = s_poff[t + 1] - s_poff[t]; }
      #pragma unroll
      for (int o = 1; o < 64; o <<= 1) {
        int u = __shfl_up(v, (unsigned)o, 64);
        if ((tid & 63) >= o) v += u;
      }
      if ((tid & 63) == 63) s_wsum[tid >> 6] = v;
      __syncthreads();
      if (tid < 16) {
        int w = s_wsum[tid];
        #pragma unroll
        for (int o = 1; o < 16; o <<= 1) {
          int u = __shfl_up(w, (unsigned)o, 16);
          if (tid >= o) w += u;
        }
        s_wsum[tid] = w;
      }
      __syncthreads();
      if (tid < nd) {
        int incl = v + ((tid >> 6) ? s_wsum[(tid >> 6) - 1] : 0);
        int cnti = s_poff[t + 1] - s_poff[t];
        int crel = incl - cnti;                    // relative to level d+1 start
        meta[lbeg + tid] = make_int2(t, (crel << 16) | cnti);
        for (int j = 0; j < cnti; ++j) s_nord[lend + crel + j] = s_ordp[s_poff[t] + j];
      }
      __syncthreads();
    } else {                             // fallback (pathological trees)
      for (int i = tid; i < nd; i += 1024) { int t2 = s_nord[lbeg + i]; s_sc[i] = s_poff[t2 + 1] - s_poff[t2]; }
      __syncthreads();
      for (int o = 1; o < nd; o <<= 1) {
        for (int i = tid; i < nd; i += 1024) s_sc2[i] = s_sc[i] + ((i >= o) ? s_sc[i - o] : 0);
        __syncthreads();
        for (int i = tid; i < nd; i += 1024) s_sc[i] = s_sc2[i];
        __syncthreads();
      }
      for (int i = tid; i < nd; i += 1024) {
        int t2 = s_nord[lbeg + i];
        int cnti = s_poff[t2 + 1] - s_poff[t2];
        int crel = s_sc[i] - cnti;
        meta[lbeg + i] = make_int2(t2, (crel << 16) | cnti);
        for (int j = 0; j < cnti; ++j) s_nord[lend + crel + j] = s_ordp[s_poff[t2] + j];
      }
      __syncthreads();
    }
  }
  {                                      // deepest level: all leaves
    const int lbeg = s_doff[maxd], lend = s_doff[maxd + 1];
    for (int i = lbeg + tid; i < lend; i += 1024)
      meta[i] = make_int2(s_nord[i], 0);
  }
  for (int i = tid; i <= maxd + 1; i += 1024) doff_g[i] = s_doff[i];
  if (tid == 0) *maxd_out = maxd;
}

// ---------------- pre-GEMM (m97 structure): 128x128 tile, global_load_lds, 4x4 acc/wave ----------------
__global__ __launch_bounds__(256) void pregemm_kernel(const unsigned short* __restrict__ Xb,
                                                      const unsigned short* __restrict__ Wpre,
                                                      unsigned short* __restrict__ XWb,
                                                      const float* __restrict__ biasC) {
  __shared__ alignas(16) unsigned short ldsA[128 * 32];   // 8 KiB, linear [128][32]
  __shared__ alignas(16) unsigned short ldsB[128 * 32];   // 8 KiB
  const int xcd = blockIdx.x & 7;
  const int w = blockIdx.x >> 3;        // 0..63
  const int tn = xcd * 4 + (w & 3);     // 0..31
  const int tm = w >> 2;                // 0..15
  const int m0 = tm * 128, n0 = tn * 128;
  const int tid = threadIdx.x;
  const int lane = tid & 63;
  const int wave = tid >> 6;
  const int wr = wave >> 1, wc = wave & 1;   // 2x2 waves, 64x64 each
  const int lr = lane & 15;
  const int kq = lane >> 4;             // 0..3
  const int srow = lane >> 2;
  const int scol = (lane & 3) << 3;
  f4 acc[4][4] = {};

  for (int k0 = 0; k0 < MD; k0 += 32) {
    #pragma unroll
    for (int c = 0; c < 2; ++c) {
      const int chunk = wave * 2 + c;   // 0..7, 16 rows per chunk (wave-uniform)
      const unsigned short* ga = Xb + (size_t)(m0 + chunk * 16 + srow) * MD + k0 + scol;
      const unsigned short* gb = Wpre + (size_t)(n0 + chunk * 16 + srow) * MD + k0 + scol;
      __builtin_amdgcn_global_load_lds((const __attribute__((address_space(1))) void*)ga,
                                       (__attribute__((address_space(3))) void*)&ldsA[chunk * 512],
                                       16, 0, 0);
      __builtin_amdgcn_global_load_lds((const __attribute__((address_space(1))) void*)gb,
                                       (__attribute__((address_space(3))) void*)&ldsB[chunk * 512],
                                       16, 0, 0);
    }
    __syncthreads();                    // compiler drains vmcnt before s_barrier
    short8 a[4], b[4];
    #pragma unroll
    for (int i = 0; i < 4; ++i) {
      a[i] = *(const short8*)&ldsA[(wr * 64 + i * 16 + lr) * 32 + kq * 8];
      b[i] = *(const short8*)&ldsB[(wc * 64 + i * 16 + lr) * 32 + kq * 8];
    }
    #pragma unroll
    for (int i = 0; i < 4; ++i)
      #pragma unroll
      for (int j = 0; j < 4; ++j)
        acc[i][j] = __builtin_amdgcn_mfma_f32_16x16x32_bf16(a[i], b[j], acc[i][j], 0, 0, 0);
    __syncthreads();
  }
  // epilogue: bias + scatter bf16 into XWb[strip][node][16]
  #pragma unroll
  for (int i = 0; i < 4; ++i)
    #pragma unroll
    for (int j = 0; j < 4; ++j)
      #pragma unroll
      for (int q = 0; q < 4; ++q) {
        const int row = m0 + wr * 64 + i * 16 + kq * 4 + q;   // node
        const int col = n0 + wc * 64 + j * 16 + lr;           // 0..4095
        const float v = acc[i][j][q] + biasC[col];
        const int g = col >> 10, cj = col & 1023;
        XWb[((size_t)(cj >> 2) * NN + row) * 16 + (g << 2) + (cj & 3)] = f2bf(v);
      }
}

// ---------------- cooperative recurrence ----------------
struct RP {
  const int2* meta;           // [NN] (node, (crel<<16)|cnt)
  const int* doff;            // [NN+2]
  const int* maxd;
  const unsigned short* XWb;  // [256 strips][NN][16] bf16 x-side preactivation (+ biases)
  unsigned short* G2;         // [GBLK][NN][16] bf16 spill (level width > CAP only)
  float* CbB;                 // [GBLK][NN][4]  fp32 spill
  unsigned short* Hb;         // [NN][1024] bf16 h (only cross-block data; LLC-coherent)
  const float* Wiouh;         // [3072][1024] fp32 (converted during LDS staging)
  const float* Wfh;           // [1024][1024] fp32
  float* out;                 // [2048]: c_root | h_root
  int* flags;                 // [GBLK] arrival flags + epoch word
};

// Hierarchical fence-free grid barrier: blocks write flag[bid]; block 0 polls all
// 256 flags and publishes a single epoch word; others poll 4B. No L2 flush.
__device__ __forceinline__ void grid_barrier(int* flags, int step) {
  asm volatile("s_waitcnt vmcnt(0)" ::: "memory");   // this wave's stores acked at LLC
  __syncthreads();                                   // all waves drained
  int* epoch = flags + GBLK;
  if (blockIdx.x == 0) {
    if (threadIdx.x < 64) {
      if (threadIdx.x == 0)
        __hip_atomic_store(&flags[0], step, __ATOMIC_RELAXED, __HIP_MEMORY_SCOPE_AGENT);
      const int base = threadIdx.x << 2;
      for (;;) {
        int a = __hip_atomic_load(&flags[base + 0], __ATOMIC_RELAXED, __HIP_MEMORY_SCOPE_AGENT);
        int b = __hip_atomic_load(&flags[base + 1], __ATOMIC_RELAXED, __HIP_MEMORY_SCOPE_AGENT);
        int c = __hip_atomic_load(&flags[base + 2], __ATOMIC_RELAXED, __HIP_MEMORY_SCOPE_AGENT);
        int d = __hip_atomic_load(&flags[base + 3], __ATOMIC_RELAXED, __HIP_MEMORY_SCOPE_AGENT);
        if (__all(a >= step && b >= step && c >= step && d >= step)) break;
        __builtin_amdgcn_s_sleep(1);
      }
      if (threadIdx.x == 0)
        __hip_atomic_store(epoch, step, __ATOMIC_RELAXED, __HIP_MEMORY_SCOPE_AGENT);
    }
  } else if (threadIdx.x == 0) {
    __hip_atomic_store(&flags[blockIdx.x], step, __ATOMIC_RELAXED, __HIP_MEMORY_SCOPE_AGENT);
    while (__hip_atomic_load(epoch, __ATOMIC_RELAXED, __HIP_MEMORY_SCOPE_AGENT) < step)
      __builtin_amdgcn_s_sleep(1);
  }
  __syncthreads();
  asm volatile("" ::: "memory");
}

// ---- gemm K-step macros: NAMED registers only (never scratch; R9 lesson) ----
// GSTEPR: MFMA + reload the A-reg with the second-half K-chunk (KB+16).
// GSTEPN: MFMA only (second half of K).
#define GSTEPR(A, KB, AP)                                                                \
  {                                                                                      \
    short8 bfrag = *(const short8*)(wb0 + (((((KB) << 2) + kq) ^ swz) << 3));            \
    if ((KB) & 1) ao = __builtin_amdgcn_mfma_f32_16x16x32_bf16(A, bfrag, ao, 0, 0, 0);   \
    else          ae = __builtin_amdgcn_mfma_f32_16x16x32_bf16(A, bfrag, ae, 0, 0, 0);   \
    A = *(const short8*)((AP) + (((KB) + 16) << 5));                                     \
  }
#define GSTEPN(A, KB)                                                                    \
  {                                                                                      \
    short8 bfrag = *(const short8*)(wb0 + (((((KB) << 2) + kq) ^ swz) << 3));            \
    if ((KB) & 1) ao = __builtin_amdgcn_mfma_f32_16x16x32_bf16(A, bfrag, ao, 0, 0, 0);   \
    else          ae = __builtin_amdgcn_mfma_f32_16x16x32_bf16(A, bfrag, ae, 0, 0, 0);   \
  }
#define LOADSET(S, AP)                                                                   \
  S##0  = *(const short8*)(AP);         S##1  = *(const short8*)((AP) + 32);             \
  S##2  = *(const short8*)((AP) + 64);  S##3  = *(const short8*)((AP) + 96);             \
  S##4  = *(const short8*)((AP) + 128); S##5  = *(const short8*)((AP) + 160);            \
  S##6  = *(const short8*)((AP) + 192); S##7  = *(const short8*)((AP) + 224);            \
  S##8  = *(const short8*)((AP) + 256); S##9  = *(const short8*)((AP) + 288);            \
  S##10 = *(const short8*)((AP) + 320); S##11 = *(const short8*)((AP) + 352);            \
  S##12 = *(const short8*)((AP) + 384); S##13 = *(const short8*)((AP) + 416);            \
  S##14 = *(const short8*)((AP) + 448); S##15 = *(const short8*)((AP) + 480);
#define HALF1(S, AP)                                                                     \
  GSTEPR(S##0, 0, AP)  GSTEPR(S##1, 1, AP)  GSTEPR(S##2, 2, AP)  GSTEPR(S##3, 3, AP)    \
  GSTEPR(S##4, 4, AP)  GSTEPR(S##5, 5, AP)  GSTEPR(S##6, 6, AP)  GSTEPR(S##7, 7, AP)    \
  GSTEPR(S##8, 8, AP)  GSTEPR(S##9, 9, AP)  GSTEPR(S##10, 10, AP) GSTEPR(S##11, 11, AP) \
  GSTEPR(S##12, 12, AP) GSTEPR(S##13, 13, AP) GSTEPR(S##14, 14, AP) GSTEPR(S##15, 15, AP)
#define HALF2(S)                                                                         \
  GSTEPN(S##0, 16)  GSTEPN(S##1, 17)  GSTEPN(S##2, 18)  GSTEPN(S##3, 19)                 \
  GSTEPN(S##4, 20)  GSTEPN(S##5, 21)  GSTEPN(S##6, 22)  GSTEPN(S##7, 23)                 \
  GSTEPN(S##8, 24)  GSTEPN(S##9, 25)  GSTEPN(S##10, 26) GSTEPN(S##11, 27)                \
  GSTEPN(S##12, 28) GSTEPN(S##13, 29) GSTEPN(S##14, 30) GSTEPN(S##15, 31)
#define TSTORE(RT)                                                                       \
  {                                                                                      \
    const int rb_ = ((RT) << 4) + (kq << 2);                                             \
    _Pragma("unroll")                                                                    \
    for (int q = 0; q < 4; ++q) {                                                        \
      const int rr = rb_ + q;                                                            \
      if (rr < nd) {                                                                     \
        unsigned short v = f2bf(ae[q] + ao[q]);                                          \
        if (rr < CAP) G2L[rr * 16 + lr] = v;                                             \
        else          G2g[(size_t)(lbeg + rr) * 16 + lr] = v;                            \
      }                                                                                  \
    }                                                                                    \
  }

__global__ __launch_bounds__(GTHR) void recur_kernel(RP p) {
  __shared__ alignas(16) unsigned short ldsW[16 * MD];   // 32 KiB W strip, swizzled
  __shared__ alignas(16) unsigned short G2L[CAP * 16];   // 32 KiB level-local G (bf16)
  __shared__ alignas(16) float CbL[2 * CAP * 4];         // 32 KiB level-local c (ping-pong)
  __shared__ int2 ldsMeta[NN];                           // 16 KiB
  __shared__ int ldsDoff[NN + 2];                        // 8 KiB
  const int tid = threadIdx.x;
  const int bid = blockIdx.x;
  const int lane = tid & 63;
  const int wave = tid >> 6;
  // XCD-swizzled strip: one XCD's 32 blocks cover a contiguous 128-col window
  const int strip = (bid & 7) * 32 + (bid >> 3);
  const int s4 = strip << 2;             // this block's 4 columns

  // Stage W strip from fp32, converting: LDS row j (0..15) = W row (j>>2)*1024 + s4 + (j&3).
  for (int idx = tid; idx < 16 * 128; idx += GTHR) {
    int j = idx >> 7, kc = idx & 127;
    int g = j >> 2, col = s4 + (j & 3);
    const float* src = (g < 3) ? (p.Wiouh + (size_t)(g * MD + col) * MD)
                               : (p.Wfh + (size_t)col * MD);
    f4 lo = *(const f4*)(src + (kc << 3));
    f4 hi = *(const f4*)(src + (kc << 3) + 4);
    *(uint4*)(ldsW + j * MD + ((kc ^ (j & 7)) << 3)) = pack8(lo, hi);
  }
  const int maxd = *p.maxd;
  for (int i = tid; i < NN; i += GTHR) ldsMeta[i] = p.meta[i];
  for (int i = tid; i <= maxd + 1; i += GTHR) ldsDoff[i] = p.doff[i];
  __syncthreads();

  const unsigned short* xwb = p.XWb + (size_t)strip * NN * 16;
  unsigned short* G2g = p.G2 + (size_t)bid * NN * 16;    // spill only
  float* CbBg = p.CbB + (size_t)bid * NN * 4;            // spill only
  const int chalf = tid & 1;             // which half of the children this thread sums

  for (int d = maxd; d >= 0; --d) {
    const int lbeg = ldsDoff[d], lend = ldsDoff[d + 1];
    const int nd = lend - lbeg;
    float* cbw = CbL + (size_t)(d & 1) * CAP * 4;        // this level's c
    const float* cbr = CbL + (size_t)((d + 1) & 1) * CAP * 4;  // child level's c

    // ---- cell: 2 threads/node (child-halves), 4 cols each; shfl_xor(1) reduce ----
    for (int ii = tid >> 1; ii < nd; ii += GTHR / 2) {
      const int2 mt = ldsMeta[lbeg + ii];
      const int t = mt.x, crel = mt.y >> 16, cnt = mt.y & 0xffff;
      const unsigned short* xwp = xwb + (size_t)t * 16;
      uint4 xa = *(const uint4*)xwp;         // i0..3, o0..3
      uint4 xb = *(const uint4*)(xwp + 8);   // u0..3, f0..3
      f4 gf; gf[0] = blo(xb.z); gf[1] = bhi(xb.z); gf[2] = blo(xb.w); gf[3] = bhi(xb.w);
      f4 gi = {0.f, 0.f, 0.f, 0.f}, go = gi, gu = gi, fc = gi;
      if (chalf == 0) {
        gi[0] = blo(xa.x); gi[1] = bhi(xa.x); gi[2] = blo(xa.y); gi[3] = bhi(xa.y);
        go[0] = blo(xa.z); go[1] = bhi(xa.z); go[2] = blo(xa.w); go[3] = bhi(xa.w);
        gu[0] = blo(xb.x); gu[1] = bhi(xb.x); gu[2] = blo(xb.y); gu[3] = bhi(xb.y);
      }
      for (int k = chalf; k < cnt; k += 2) {
        const int ci = crel + k;
        uint4 ga, gb; f4 cu;
        if (ci < CAP) {                       // LDS-resident child (normal path)
          ga = *(const uint4*)(G2L + ci * 16);
          gb = *(const uint4*)(G2L + ci * 16 + 8);
          cu = *(const f4*)(cbr + ci * 4);
        } else {                              // spill (level wider than CAP)
          const unsigned short* g2 = G2g + (size_t)(lend + ci) * 16;
          ga = *(const uint4*)(g2);
          gb = *(const uint4*)(g2 + 8);
          cu = *(const f4*)(CbBg + (size_t)(lend + ci) * 4);
        }
        gi[0] += blo(ga.x); gi[1] += bhi(ga.x); gi[2] += blo(ga.y); gi[3] += bhi(ga.y);
        go[0] += blo(ga.z); go[1] += bhi(ga.z); go[2] += blo(ga.w); go[3] += bhi(ga.w);
        gu[0] += blo(gb.x); gu[1] += bhi(gb.x); gu[2] += blo(gb.y); gu[3] += bhi(gb.y);
        f4 gff; gff[0] = blo(gb.z); gff[1] = bhi(gb.z); gff[2] = blo(gb.w); gff[3] = bhi(gb.w);
        #pragma unroll
        for (int q = 0; q < 4; ++q) fc[q] += sigm(gff[q] + gf[q]) * cu[q];
      }
      #pragma unroll
      for (int q = 0; q < 4; ++q) {          // pairwise reduce the two child-halves
        gi[q] += __shfl_xor(gi[q], 1);
        go[q] += __shfl_xor(go[q], 1);
        gu[q] += __shfl_xor(gu[q], 1);
        fc[q] += __shfl_xor(fc[q], 1);
      }
      if (chalf == 0) {
        f4 cv, hv;
        #pragma unroll
        for (int q = 0; q < 4; ++q) {
          float c0 = sigm(gi[q]) * tanh_(gu[q]) + fc[q];
          cv[q] = c0;
          hv[q] = sigm(go[q]) * tanh_(c0);
        }
        if (ii < CAP) *(f4*)(cbw + ii * 4) = cv;
        else          *(f4*)(CbBg + (size_t)(lbeg + ii) * 4) = cv;
        unsigned long long hp =
            (unsigned long long)f2bf(hv[0]) |
            ((unsigned long long)f2bf(hv[1]) << 16) |
            ((unsigned long long)f2bf(hv[2]) << 32) |
            ((unsigned long long)f2bf(hv[3]) << 48);
        __hip_atomic_store((unsigned long long*)(p.Hb + (size_t)t * MD + s4),
                           hp, __ATOMIC_RELAXED, __HIP_MEMORY_SCOPE_AGENT);
        if (t == NN - 1) {                   // root: output (c | h) fp32
          *(f4*)(p.out + s4) = cv;
          *(f4*)(p.out + MD + s4) = hv;
        }
      }
    }
    if (d == 0) break;

    // ---- grid barrier: h of level d now visible at LLC (also block-syncs) ----
    grid_barrier(p.flags, maxd - d + 1);

    // ---- prefetch next level's XWb lines into L2 (hides LLC latency for the cell) ----
    if (d > 0) {
      const int lbeg2 = ldsDoff[d - 1];
      const int nd2 = lbeg - lbeg2;
      for (int q2 = tid; q2 < nd2; q2 += GTHR) {
        unsigned v = *(const unsigned*)(xwb + (size_t)ldsMeta[lbeg2 + q2].x * 16);
        asm volatile("" :: "v"(v));      // keep-alive (no DCE)
      }
    }

    // ---- gemm: G2L[rr][0..15] = h[node(rr)] @ Wstrip^T (16 G-cols) ----
    // Cross-tile double-buffered A-pipeline: next tile's 16 loads issue into the
    // OTHER named register set between the current tile's two K-halves, hiding
    // the inter-tile LLC RTT (R11 showed intra-tile depth alone is not the lever).
    {
      const int ntr = (nd + 15) >> 4;
      const int lr = lane & 15;
      const int kq = lane >> 4;
      const int swz = lr & 7;
      const unsigned short* wb0 = ldsW + lr * MD;
      short8 Aa0, Aa1, Aa2, Aa3, Aa4, Aa5, Aa6, Aa7,
             Aa8, Aa9, Aa10, Aa11, Aa12, Aa13, Aa14, Aa15;
      short8 Ab0, Ab1, Ab2, Ab3, Ab4, Ab5, Ab6, Ab7,
             Ab8, Ab9, Ab10, Ab11, Ab12, Ab13, Ab14, Ab15;
      const unsigned short* apA = p.Hb;
      const unsigned short* apB = p.Hb;
      f4 ae, ao;
      int rt = wave;
      if (rt < ntr) {
        const int r = (rt << 4) + lr;
        const int pos = lbeg + ((r < nd) ? r : 0);
        apA = p.Hb + (size_t)ldsMeta[pos].x * MD + (kq << 3);
        LOADSET(Aa, apA)
      }
      while (rt < ntr) {
        int rtn = rt + (GTHR / 64);
        // ---- tile in set A ----
        ae = (f4){0.f, 0.f, 0.f, 0.f}; ao = ae;
        HALF1(Aa, apA)
        if (rtn < ntr) {                     // issue next tile's loads into set B
          const int r2 = (rtn << 4) + lr;
          const int pos2 = lbeg + ((r2 < nd) ? r2 : 0);
          apB = p.Hb + (size_t)ldsMeta[pos2].x * MD + (kq << 3);
          LOADSET(Ab, apB)
        }
        HALF2(Aa)
        TSTORE(rt)
        rt = rtn;
        if (rt >= ntr) break;
        rtn = rt + (GTHR / 64);
        // ---- tile in set B ----
        ae = (f4){0.f, 0.f, 0.f, 0.f}; ao = ae;
        HALF1(Ab, apB)
        if (rtn < ntr) {                     // issue next tile's loads into set A
          const int r3 = (rtn << 4) + lr;
          const int pos3 = lbeg + ((r3 < nd) ? r3 : 0);
          apA = p.Hb + (size_t)ldsMeta[pos3].x * MD + (kq << 3);
          LOADSET(Aa, apA)
        }
        HALF2(Ab)
        TSTORE(rt)
        rt = rtn;
      }
    }
    __syncthreads();   // G2L/CbL handoff to next cell
  }
}

// ---------------- launch ----------------
extern "C" void kernel_launch(void* const* d_in, const int* in_sizes, int n_in,
                              void* d_out, int out_size, void* d_ws, size_t ws_size,
                              hipStream_t stream) {
  const float* X     = (const float*)d_in[0];
  const int*   parent= (const int*)d_in[1];
  const float* Wioux = (const float*)d_in[2];
  const float* bioux = (const float*)d_in[3];
  const float* Wiouh = (const float*)d_in[4];
  const float* biouh = (const float*)d_in[5];
  const float* Wfx   = (const float*)d_in[6];
  const float* bfx   = (const float*)d_in[7];
  const float* Wfh   = (const float*)d_in[8];
  const float* bfh   = (const float*)d_in[9];
  float* out = (float*)d_out;

  char* ws = (char*)d_ws;
  size_t o = 0;
  auto alloc = [&](size_t bytes) { size_t r = o; o += (bytes + 255) & ~(size_t)255; return r; };
  unsigned short* Xb   = (unsigned short*)(ws + alloc((size_t)NN * MD * 2));
  unsigned short* Wpre = (unsigned short*)(ws + alloc((size_t)NOUT * MD * 2));
  unsigned short* XWb  = (unsigned short*)(ws + alloc((size_t)GBLK * NN * 16 * 2));
  unsigned short* G2   = (unsigned short*)(ws + alloc((size_t)GBLK * NN * 16 * 2));
  float* CbB           = (float*)(ws + alloc((size_t)GBLK * NN * 4 * 4));
  unsigned short* Hb   = (unsigned short*)(ws + alloc((size_t)NN * MD * 2));
  float* biasC         = (float*)(ws + alloc((size_t)NOUT * 4));
  int2* meta           = (int2*)(ws + alloc((size_t)NN * 8));
  int* doff            = (int*)(ws + alloc((NN + 4) * 4));
  int* maxd            = (int*)(ws + alloc(256));
  int* flags           = (int*)(ws + alloc((GBLK + 64) * 4));

  // fused: block 0 = prep (dispatched first, overlaps cvt); blocks 1.. = cvt
  {
    const int n4 = (NN * MD + 3072 * MD + 1024 * MD) / 4;
    const int cvt_blocks = (n4 + 1023) / 1024;
    cvt_prep_kernel<<<cvt_blocks + 1, 1024, 0, stream>>>(
        X, Wioux, Wfx, Xb, Wpre,
        parent, meta, doff, maxd, flags,
        bioux, biouh, bfx, bfh, biasC);
  }

  pregemm_kernel<<<(NN / 128) * (NOUT / 128), 256, 0, stream>>>(Xb, Wpre, XWb, biasC);

  RP p;
  p.meta = meta; p.doff = doff; p.maxd = maxd;
  p.XWb = XWb; p.G2 = G2; p.CbB = CbB; p.Hb = Hb;
  p.Wiouh = Wiouh; p.Wfh = Wfh;
  p.out = out; p.flags = flags;
  void* args[] = {&p};
  hipLaunchCooperativeKernel((const void*)recur_kernel, dim3(GBLK), dim3(GTHR), args, 0, stream);

  (void)in_sizes; (void)n_in; (void)out_size; (void)ws_size;
}

// Round 16
// 322.456 us; speedup vs baseline: 1.4480x; 1.4480x over previous
//
#include <hip/hip_runtime.h>

#define NN 2048          // nodes
#define MD 1024          // mem/input dim
#define NOUT 4096        // 3M (iou) + M (f) output columns
#define GBLK 256         // cooperative grid blocks: one 4-col strip each
#define GTHR 512         // threads per block (8 waves); LDS-bound 1 blk/CU -> VGPR free to 256
#define CAP 1024         // max level width held in LDS (spill to global beyond)

typedef __attribute__((ext_vector_type(8))) short short8;   // 8 x bf16 fragment
typedef __attribute__((ext_vector_type(4))) float f4;

__device__ __forceinline__ unsigned short f2bf(float f) {
  unsigned u = __float_as_uint(f);
  u += 0x7fffu + ((u >> 16) & 1u);      // RNE
  return (unsigned short)(u >> 16);
}
__device__ __forceinline__ uint4 pack8(f4 a, f4 b) {
  uint4 r;
  r.x = f2bf(a[0]) | ((unsigned)f2bf(a[1]) << 16);
  r.y = f2bf(a[2]) | ((unsigned)f2bf(a[3]) << 16);
  r.z = f2bf(b[0]) | ((unsigned)f2bf(b[1]) << 16);
  r.w = f2bf(b[2]) | ((unsigned)f2bf(b[3]) << 16);
  return r;
}
__device__ __forceinline__ float blo(unsigned u) { return __uint_as_float(u << 16); }
__device__ __forceinline__ float bhi(unsigned u) { return __uint_as_float(u & 0xffff0000u); }
__device__ __forceinline__ float sigm(float x) { return 1.0f / (1.0f + __expf(-x)); }
__device__ __forceinline__ float tanh_(float x) { return 1.0f - 2.0f / (1.0f + __expf(2.0f * x)); }

// ---------------- fused cvt + prep kernel (1024 threads) ----------------
// Block 0: full prep (depth, parent-sort, BFS order, biasC, flag reset).
// Blocks 1..: grid-stride fp32->bf16 of X, Wioux, Wfx.
__global__ __launch_bounds__(1024) void cvt_prep_kernel(const float* __restrict__ X,
                                                        const float* __restrict__ Wioux,
                                                        const float* __restrict__ Wfx,
                                                        unsigned short* __restrict__ Xb,
                                                        unsigned short* __restrict__ Wpre,
                                                        const int* __restrict__ parent,
                                                        int2* __restrict__ meta,
                                                        int* __restrict__ doff_g,
                                                        int* __restrict__ maxd_out,
                                                        int* __restrict__ flags,
                                                        const float* __restrict__ bioux,
                                                        const float* __restrict__ biouh,
                                                        const float* __restrict__ bfx,
                                                        const float* __restrict__ bfh,
                                                        float* __restrict__ biasC) {
  __shared__ int s_anc[NN], s_dep[NN];
  __shared__ int s_t1[NN + 2], s_t2[NN + 2];
  __shared__ int s_poff[NN + 2], s_cur[NN + 2];
  __shared__ int s_ordp[NN], s_nord[NN];
  __shared__ int s_doff[NN + 2];
  __shared__ int s_sc[NN], s_sc2[NN];
  __shared__ int s_wsum[17];
  __shared__ int s_maxd;
  const int tid = threadIdx.x;

  if (blockIdx.x != 0) {                 // ---------- cvt part ----------
    const int nX = NN * MD / 4;
    const int nWi = 3072 * MD / 4;
    const int nWf = 1024 * MD / 4;
    int i = (blockIdx.x - 1) * 1024 + tid;
    const float* s; unsigned short* d; int off;
    if (i < nX) { s = X; d = Xb; off = i; }
    else if (i < nX + nWi) { s = Wioux; d = Wpre; off = i - nX; }
    else if (i < nX + nWi + nWf) { s = Wfx; d = Wpre + (size_t)3072 * MD; off = i - nX - nWi; }
    else return;
    f4 v = *((const f4*)s + off);
    uint2 r;
    r.x = f2bf(v[0]) | ((unsigned)f2bf(v[1]) << 16);
    r.y = f2bf(v[2]) | ((unsigned)f2bf(v[3]) << 16);
    *((uint2*)d + off) = r;
    return;
  }

  // ---------- prep part (block 0 only) ----------
  if (tid == 0) s_maxd = 0;
  for (int i = tid; i < GBLK + 64; i += 1024) flags[i] = 0;   // reset barrier epochs
  for (int i = tid; i < NOUT; i += 1024)                       // combined bias
    biasC[i] = (i < 3072) ? (bioux[i] + biouh[i]) : (bfx[i - 3072] + bfh[i - 3072]);
  for (int t = tid; t < NN; t += 1024) {
    bool root = (t == NN - 1);
    s_anc[t] = root ? t : parent[t];
    s_dep[t] = root ? 0 : 1;
  }
  __syncthreads();
  for (int it = 0; it < 11; ++it) {     // 2^11 >= NN
    for (int t = tid; t < NN; t += 1024) { int a = s_anc[t]; s_t1[t] = s_dep[t] + s_dep[a]; s_t2[t] = s_anc[a]; }
    __syncthreads();
    for (int t = tid; t < NN; t += 1024) { s_dep[t] = s_t1[t]; s_anc[t] = s_t2[t]; }
    __syncthreads();
  }
  for (int t = tid; t < NN; t += 1024) atomicMax(&s_maxd, s_dep[t]);

  // ---- counting sort by parent -> s_ordp with offsets s_poff ----
  for (int i = tid; i < NN + 2; i += 1024) s_t2[i] = 0;
  __syncthreads();
  for (int t = tid; t < NN; t += 1024) atomicAdd(&s_t2[parent[t]], 1);
  __syncthreads();
  {
    const int L = NN + 2;
    int* src = s_t2; int* dst = s_t1;
    for (int o = 1; o < L; o <<= 1) {
      for (int i = tid; i < L; i += 1024) dst[i] = src[i] + ((i >= o) ? src[i - o] : 0);
      __syncthreads();
      int* tmp = src; src = dst; dst = tmp;
    }
    for (int i = tid; i < L; i += 1024) { int v = (i ? src[i - 1] : 0); s_poff[i] = v; s_cur[i] = v; }
    __syncthreads();
    for (int t = tid; t < NN; t += 1024) {
      int pos = atomicAdd(&s_cur[parent[t]], 1);
      s_ordp[pos] = t;
    }
    __syncthreads();
    for (int p = tid; p < NN + 1; p += 1024) {    // determinism within bucket
      int b = s_poff[p], e = s_poff[p + 1];
      for (int i = b + 1; i < e; ++i) {
        int v = s_ordp[i], j = i - 1;
        while (j >= b && s_ordp[j] > v) { s_ordp[j + 1] = s_ordp[j]; --j; }
        s_ordp[j + 1] = v;
      }
    }
    __syncthreads();
  }

  // ---- counts by depth -> s_doff ----
  for (int i = tid; i < NN + 2; i += 1024) s_t2[i] = 0;
  __syncthreads();
  for (int t = tid; t < NN; t += 1024) atomicAdd(&s_t2[s_dep[t]], 1);
  __syncthreads();
  {
    const int L = NN + 1;
    int* src = s_t2; int* dst = s_t1;
    for (int o = 1; o < L; o <<= 1) {
      for (int i = tid; i < L; i += 1024) dst[i] = src[i] + ((i >= o) ? src[i - o] : 0);
      __syncthreads();
      int* tmp = src; src = dst; dst = tmp;
    }
    for (int i = tid; i < L + 1; i += 1024) s_doff[i] = (i ? src[i - 1] : 0);
    __syncthreads();
  }

  // ---- BFS: parent-grouped order per level; child indices level-relative ----
  const int maxd = s_maxd;
  if (tid == 0) s_nord[0] = NN - 1;     // root at position 0
  __syncthreads();
  for (int d = 0; d < maxd; ++d) {
    const int lbeg = s_doff[d], lend = s_doff[d + 1];
    const int nd = lend - lbeg;
    if (nd <= 1024) {
      int t = -1, v = 0;
      if (tid < nd) { t = s_nord[lbeg + tid]; v = s_poff[t + 1] - s_poff[t]; }
      #pragma unroll
      for (int o = 1; o < 64; o <<= 1) {
        int u = __shfl_up(v, (unsigned)o, 64);
        if ((tid & 63) >= o) v += u;
      }
      if ((tid & 63) == 63) s_wsum[tid >> 6] = v;
      __syncthreads();
      if (tid < 16) {
        int w = s_wsum[tid];
        #pragma unroll
        for (int o = 1; o < 16; o <<= 1) {
          int u = __shfl_up(w, (unsigned)o, 16);
          if (tid >= o) w += u;
        }
        s_wsum[tid] = w;
      }
      __syncthreads();
      if (tid < nd) {
        int incl = v + ((tid >> 6) ? s_wsum[(tid >> 6) - 1] : 0);
        int cnti = s_poff[t + 1] - s_poff[t];
        int crel = incl - cnti;                    // relative to level d+1 start
        meta[lbeg + tid] = make_int2(t, (crel << 16) | cnti);
        for (int j = 0; j < cnti; ++j) s_nord[lend + crel + j] = s_ordp[s_poff[t] + j];
      }
      __syncthreads();
    } else {                             // fallback (pathological trees)
      for (int i = tid; i < nd; i += 1024) { int t2 = s_nord[lbeg + i]; s_sc[i] = s_poff[t2 + 1] - s_poff[t2]; }
      __syncthreads();
      for (int o = 1; o < nd; o <<= 1) {
        for (int i = tid; i < nd; i += 1024) s_sc2[i] = s_sc[i] + ((i >= o) ? s_sc[i - o] : 0);
        __syncthreads();
        for (int i = tid; i < nd; i += 1024) s_sc[i] = s_sc2[i];
        __syncthreads();
      }
      for (int i = tid; i < nd; i += 1024) {
        int t2 = s_nord[lbeg + i];
        int cnti = s_poff[t2 + 1] - s_poff[t2];
        int crel = s_sc[i] - cnti;
        meta[lbeg + i] = make_int2(t2, (crel << 16) | cnti);
        for (int j = 0; j < cnti; ++j) s_nord[lend + crel + j] = s_ordp[s_poff[t2] + j];
      }
      __syncthreads();
    }
  }
  {                                      // deepest level: all leaves
    const int lbeg = s_doff[maxd], lend = s_doff[maxd + 1];
    for (int i = lbeg + tid; i < lend; i += 1024)
      meta[i] = make_int2(s_nord[i], 0);
  }
  for (int i = tid; i <= maxd + 1; i += 1024) doff_g[i] = s_doff[i];
  if (tid == 0) *maxd_out = maxd;
}

// ---------------- pre-GEMM (m97 structure): 128x128 tile, global_load_lds, 4x4 acc/wave ----------------
__global__ __launch_bounds__(256) void pregemm_kernel(const unsigned short* __restrict__ Xb,
                                                      const unsigned short* __restrict__ Wpre,
                                                      unsigned short* __restrict__ XWb,
                                                      const float* __restrict__ biasC) {
  __shared__ alignas(16) unsigned short ldsA[128 * 32];   // 8 KiB, linear [128][32]
  __shared__ alignas(16) unsigned short ldsB[128 * 32];   // 8 KiB
  const int xcd = blockIdx.x & 7;
  const int w = blockIdx.x >> 3;        // 0..63
  const int tn = xcd * 4 + (w & 3);     // 0..31
  const int tm = w >> 2;                // 0..15
  const int m0 = tm * 128, n0 = tn * 128;
  const int tid = threadIdx.x;
  const int lane = tid & 63;
  const int wave = tid >> 6;
  const int wr = wave >> 1, wc = wave & 1;   // 2x2 waves, 64x64 each
  const int lr = lane & 15;
  const int kq = lane >> 4;             // 0..3
  const int srow = lane >> 2;
  const int scol = (lane & 3) << 3;
  f4 acc[4][4] = {};

  for (int k0 = 0; k0 < MD; k0 += 32) {
    #pragma unroll
    for (int c = 0; c < 2; ++c) {
      const int chunk = wave * 2 + c;   // 0..7, 16 rows per chunk (wave-uniform)
      const unsigned short* ga = Xb + (size_t)(m0 + chunk * 16 + srow) * MD + k0 + scol;
      const unsigned short* gb = Wpre + (size_t)(n0 + chunk * 16 + srow) * MD + k0 + scol;
      __builtin_amdgcn_global_load_lds((const __attribute__((address_space(1))) void*)ga,
                                       (__attribute__((address_space(3))) void*)&ldsA[chunk * 512],
                                       16, 0, 0);
      __builtin_amdgcn_global_load_lds((const __attribute__((address_space(1))) void*)gb,
                                       (__attribute__((address_space(3))) void*)&ldsB[chunk * 512],
                                       16, 0, 0);
    }
    __syncthreads();                    // compiler drains vmcnt before s_barrier
    short8 a[4], b[4];
    #pragma unroll
    for (int i = 0; i < 4; ++i) {
      a[i] = *(const short8*)&ldsA[(wr * 64 + i * 16 + lr) * 32 + kq * 8];
      b[i] = *(const short8*)&ldsB[(wc * 64 + i * 16 + lr) * 32 + kq * 8];
    }
    #pragma unroll
    for (int i = 0; i < 4; ++i)
      #pragma unroll
      for (int j = 0; j < 4; ++j)
        acc[i][j] = __builtin_amdgcn_mfma_f32_16x16x32_bf16(a[i], b[j], acc[i][j], 0, 0, 0);
    __syncthreads();
  }
  // epilogue: bias + scatter bf16 into XWb[strip][node][16]
  #pragma unroll
  for (int i = 0; i < 4; ++i)
    #pragma unroll
    for (int j = 0; j < 4; ++j)
      #pragma unroll
      for (int q = 0; q < 4; ++q) {
        const int row = m0 + wr * 64 + i * 16 + kq * 4 + q;   // node
        const int col = n0 + wc * 64 + j * 16 + lr;           // 0..4095
        const float v = acc[i][j][q] + biasC[col];
        const int g = col >> 10, cj = col & 1023;
        XWb[((size_t)(cj >> 2) * NN + row) * 16 + (g << 2) + (cj & 3)] = f2bf(v);
      }
}

// ---------------- cooperative recurrence (R14 config: hierarchical barrier,
// prefetch AFTER barrier, single 16-deep named-register A pipeline) ----------------
struct RP {
  const int2* meta;           // [NN] (node, (crel<<16)|cnt)
  const int* doff;            // [NN+2]
  const int* maxd;
  const unsigned short* XWb;  // [256 strips][NN][16] bf16 x-side preactivation (+ biases)
  unsigned short* G2;         // [GBLK][NN][16] bf16 spill (level width > CAP only)
  float* CbB;                 // [GBLK][NN][4]  fp32 spill
  unsigned short* Hb;         // [NN][1024] bf16 h (only cross-block data; LLC-coherent)
  const float* Wiouh;         // [3072][1024] fp32 (converted during LDS staging)
  const float* Wfh;           // [1024][1024] fp32
  float* out;                 // [2048]: c_root | h_root
  int* flags;                 // [GBLK] arrival flags + epoch word
};

// Hierarchical fence-free grid barrier: blocks write flag[bid]; block 0 polls all
// 256 flags and publishes a single epoch word; others poll 4B. No L2 flush.
__device__ __forceinline__ void grid_barrier(int* flags, int step) {
  asm volatile("s_waitcnt vmcnt(0)" ::: "memory");   // this wave's stores acked at LLC
  __syncthreads();                                   // all waves drained
  int* epoch = flags + GBLK;
  if (blockIdx.x == 0) {
    if (threadIdx.x < 64) {
      if (threadIdx.x == 0)
        __hip_atomic_store(&flags[0], step, __ATOMIC_RELAXED, __HIP_MEMORY_SCOPE_AGENT);
      const int base = threadIdx.x << 2;
      for (;;) {
        int a = __hip_atomic_load(&flags[base + 0], __ATOMIC_RELAXED, __HIP_MEMORY_SCOPE_AGENT);
        int b = __hip_atomic_load(&flags[base + 1], __ATOMIC_RELAXED, __HIP_MEMORY_SCOPE_AGENT);
        int c = __hip_atomic_load(&flags[base + 2], __ATOMIC_RELAXED, __HIP_MEMORY_SCOPE_AGENT);
        int d = __hip_atomic_load(&flags[base + 3], __ATOMIC_RELAXED, __HIP_MEMORY_SCOPE_AGENT);
        if (__all(a >= step && b >= step && c >= step && d >= step)) break;
        __builtin_amdgcn_s_sleep(1);
      }
      if (threadIdx.x == 0)
        __hip_atomic_store(epoch, step, __ATOMIC_RELAXED, __HIP_MEMORY_SCOPE_AGENT);
    }
  } else if (threadIdx.x == 0) {
    __hip_atomic_store(&flags[blockIdx.x], step, __ATOMIC_RELAXED, __HIP_MEMORY_SCOPE_AGENT);
    while (__hip_atomic_load(epoch, __ATOMIC_RELAXED, __HIP_MEMORY_SCOPE_AGENT) < step)
      __builtin_amdgcn_s_sleep(1);
  }
  __syncthreads();
  asm volatile("" ::: "memory");
}

// one K=32 slice: b-frag from LDS, MFMA into alternating acc, prefetch A 16 ahead.
// A is a NAMED register (never an indexed array -> never scratch; R9 lesson).
// Single 16-deep set: fits the 512-thr VGPR budget (104 used); two sets spill (R15).
#define GSTEP(A, KB)                                                                     \
  {                                                                                      \
    short8 bfrag = *(const short8*)(wb0 + ((((KB << 2) + kq) ^ swz) << 3));              \
    if ((KB) & 1) ao = __builtin_amdgcn_mfma_f32_16x16x32_bf16(A, bfrag, ao, 0, 0, 0);   \
    else          ae = __builtin_amdgcn_mfma_f32_16x16x32_bf16(A, bfrag, ae, 0, 0, 0);   \
    if ((KB) + 16 < 32) A = *(const short8*)(ap + (((KB) + 16) << 5));                   \
  }

__global__ __launch_bounds__(GTHR) void recur_kernel(RP p) {
  __shared__ alignas(16) unsigned short ldsW[16 * MD];   // 32 KiB W strip, swizzled
  __shared__ alignas(16) unsigned short G2L[CAP * 16];   // 32 KiB level-local G (bf16)
  __shared__ alignas(16) float CbL[2 * CAP * 4];         // 32 KiB level-local c (ping-pong)
  __shared__ int2 ldsMeta[NN];                           // 16 KiB
  __shared__ int ldsDoff[NN + 2];                        // 8 KiB
  const int tid = threadIdx.x;
  const int bid = blockIdx.x;
  const int lane = tid & 63;
  const int wave = tid >> 6;
  // XCD-swizzled strip: one XCD's 32 blocks cover a contiguous 128-col window
  const int strip = (bid & 7) * 32 + (bid >> 3);
  const int s4 = strip << 2;             // this block's 4 columns

  // Stage W strip from fp32, converting: LDS row j (0..15) = W row (j>>2)*1024 + s4 + (j&3).
  for (int idx = tid; idx < 16 * 128; idx += GTHR) {
    int j = idx >> 7, kc = idx & 127;
    int g = j >> 2, col = s4 + (j & 3);
    const float* src = (g < 3) ? (p.Wiouh + (size_t)(g * MD + col) * MD)
                               : (p.Wfh + (size_t)col * MD);
    f4 lo = *(const f4*)(src + (kc << 3));
    f4 hi = *(const f4*)(src + (kc << 3) + 4);
    *(uint4*)(ldsW + j * MD + ((kc ^ (j & 7)) << 3)) = pack8(lo, hi);
  }
  const int maxd = *p.maxd;
  for (int i = tid; i < NN; i += GTHR) ldsMeta[i] = p.meta[i];
  for (int i = tid; i <= maxd + 1; i += GTHR) ldsDoff[i] = p.doff[i];
  __syncthreads();

  const unsigned short* xwb = p.XWb + (size_t)strip * NN * 16;
  unsigned short* G2g = p.G2 + (size_t)bid * NN * 16;    // spill only
  float* CbBg = p.CbB + (size_t)bid * NN * 4;            // spill only
  const int chalf = tid & 1;             // which half of the children this thread sums

  for (int d = maxd; d >= 0; --d) {
    const int lbeg = ldsDoff[d], lend = ldsDoff[d + 1];
    const int nd = lend - lbeg;
    float* cbw = CbL + (size_t)(d & 1) * CAP * 4;        // this level's c
    const float* cbr = CbL + (size_t)((d + 1) & 1) * CAP * 4;  // child level's c

    // ---- cell: 2 threads/node (child-halves), 4 cols each; shfl_xor(1) reduce ----
    for (int ii = tid >> 1; ii < nd; ii += GTHR / 2) {
      const int2 mt = ldsMeta[lbeg + ii];
      const int t = mt.x, crel = mt.y >> 16, cnt = mt.y & 0xffff;
      const unsigned short* xwp = xwb + (size_t)t * 16;
      uint4 xa = *(const uint4*)xwp;         // i0..3, o0..3
      uint4 xb = *(const uint4*)(xwp + 8);   // u0..3, f0..3
      f4 gf; gf[0] = blo(xb.z); gf[1] = bhi(xb.z); gf[2] = blo(xb.w); gf[3] = bhi(xb.w);
      f4 gi = {0.f, 0.f, 0.f, 0.f}, go = gi, gu = gi, fc = gi;
      if (chalf == 0) {
        gi[0] = blo(xa.x); gi[1] = bhi(xa.x); gi[2] = blo(xa.y); gi[3] = bhi(xa.y);
        go[0] = blo(xa.z); go[1] = bhi(xa.z); go[2] = blo(xa.w); go[3] = bhi(xa.w);
        gu[0] = blo(xb.x); gu[1] = bhi(xb.x); gu[2] = blo(xb.y); gu[3] = bhi(xb.y);
      }
      for (int k = chalf; k < cnt; k += 2) {
        const int ci = crel + k;
        uint4 ga, gb; f4 cu;
        if (ci < CAP) {                       // LDS-resident child (normal path)
          ga = *(const uint4*)(G2L + ci * 16);
          gb = *(const uint4*)(G2L + ci * 16 + 8);
          cu = *(const f4*)(cbr + ci * 4);
        } else {                              // spill (level wider than CAP)
          const unsigned short* g2 = G2g + (size_t)(lend + ci) * 16;
          ga = *(const uint4*)(g2);
          gb = *(const uint4*)(g2 + 8);
          cu = *(const f4*)(CbBg + (size_t)(lend + ci) * 4);
        }
        gi[0] += blo(ga.x); gi[1] += bhi(ga.x); gi[2] += blo(ga.y); gi[3] += bhi(ga.y);
        go[0] += blo(ga.z); go[1] += bhi(ga.z); go[2] += blo(ga.w); go[3] += bhi(ga.w);
        gu[0] += blo(gb.x); gu[1] += bhi(gb.x); gu[2] += blo(gb.y); gu[3] += bhi(gb.y);
        f4 gff; gff[0] = blo(gb.z); gff[1] = bhi(gb.z); gff[2] = blo(gb.w); gff[3] = bhi(gb.w);
        #pragma unroll
        for (int q = 0; q < 4; ++q) fc[q] += sigm(gff[q] + gf[q]) * cu[q];
      }
      #pragma unroll
      for (int q = 0; q < 4; ++q) {          // pairwise reduce the two child-halves
        gi[q] += __shfl_xor(gi[q], 1);
        go[q] += __shfl_xor(go[q], 1);
        gu[q] += __shfl_xor(gu[q], 1);
        fc[q] += __shfl_xor(fc[q], 1);
      }
      if (chalf == 0) {
        f4 cv, hv;
        #pragma unroll
        for (int q = 0; q < 4; ++q) {
          float c0 = sigm(gi[q]) * tanh_(gu[q]) + fc[q];
          cv[q] = c0;
          hv[q] = sigm(go[q]) * tanh_(c0);
        }
        if (ii < CAP) *(f4*)(cbw + ii * 4) = cv;
        else          *(f4*)(CbBg + (size_t)(lbeg + ii) * 4) = cv;
        unsigned long long hp =
            (unsigned long long)f2bf(hv[0]) |
            ((unsigned long long)f2bf(hv[1]) << 16) |
            ((unsigned long long)f2bf(hv[2]) << 32) |
            ((unsigned long long)f2bf(hv[3]) << 48);
        __hip_atomic_store((unsigned long long*)(p.Hb + (size_t)t * MD + s4),
                           hp, __ATOMIC_RELAXED, __HIP_MEMORY_SCOPE_AGENT);
        if (t == NN - 1) {                   // root: output (c | h) fp32
          *(f4*)(p.out + s4) = cv;
          *(f4*)(p.out + MD + s4) = hv;
        }
      }
    }
    if (d == 0) break;

    // ---- grid barrier: h of level d now visible at LLC (also block-syncs) ----
    grid_barrier(p.flags, maxd - d + 1);

    // ---- prefetch next level's XWb lines into L2 (hides LLC latency for the cell) ----
    if (d > 0) {
      const int lbeg2 = ldsDoff[d - 1];
      const int nd2 = lbeg - lbeg2;
      for (int q2 = tid; q2 < nd2; q2 += GTHR) {
        unsigned v = *(const unsigned*)(xwb + (size_t)ldsMeta[lbeg2 + q2].x * 16);
        asm volatile("" :: "v"(v));      // keep-alive (no DCE)
      }
    }

    // ---- gemm: G2L[rr][0..15] = h[node(rr)] @ Wstrip^T (16 G-cols) ----
    // 16-deep NAMED-register A pipeline (no indexed array -> no scratch).
    {
      const int ntr = (nd + 15) >> 4;
      const int lr = lane & 15;
      const int kq = lane >> 4;
      const int swz = lr & 7;
      const unsigned short* wb0 = ldsW + lr * MD;
      for (int rt = wave; rt < ntr; rt += GTHR / 64) {
        const int r = (rt << 4) + lr;
        const int pos = lbeg + ((r < nd) ? r : 0);
        const int node = ldsMeta[pos].x;
        const unsigned short* ap = p.Hb + (size_t)node * MD + (kq << 3);
        short8 A0  = *(const short8*)(ap);
        short8 A1  = *(const short8*)(ap + 32);
        short8 A2  = *(const short8*)(ap + 64);
        short8 A3  = *(const short8*)(ap + 96);
        short8 A4  = *(const short8*)(ap + 128);
        short8 A5  = *(const short8*)(ap + 160);
        short8 A6  = *(const short8*)(ap + 192);
        short8 A7  = *(const short8*)(ap + 224);
        short8 A8  = *(const short8*)(ap + 256);
        short8 A9  = *(const short8*)(ap + 288);
        short8 A10 = *(const short8*)(ap + 320);
        short8 A11 = *(const short8*)(ap + 352);
        short8 A12 = *(const short8*)(ap + 384);
        short8 A13 = *(const short8*)(ap + 416);
        short8 A14 = *(const short8*)(ap + 448);
        short8 A15 = *(const short8*)(ap + 480);
        f4 ae = {0.f, 0.f, 0.f, 0.f}, ao = {0.f, 0.f, 0.f, 0.f};
        GSTEP(A0, 0)   GSTEP(A1, 1)   GSTEP(A2, 2)   GSTEP(A3, 3)
        GSTEP(A4, 4)   GSTEP(A5, 5)   GSTEP(A6, 6)   GSTEP(A7, 7)
        GSTEP(A8, 8)   GSTEP(A9, 9)   GSTEP(A10, 10) GSTEP(A11, 11)
        GSTEP(A12, 12) GSTEP(A13, 13) GSTEP(A14, 14) GSTEP(A15, 15)
        GSTEP(A0, 16)  GSTEP(A1, 17)  GSTEP(A2, 18)  GSTEP(A3, 19)
        GSTEP(A4, 20)  GSTEP(A5, 21)  GSTEP(A6, 22)  GSTEP(A7, 23)
        GSTEP(A8, 24)  GSTEP(A9, 25)  GSTEP(A10, 26) GSTEP(A11, 27)
        GSTEP(A12, 28) GSTEP(A13, 29) GSTEP(A14, 30) GSTEP(A15, 31)
        const int rb = (rt << 4) + (kq << 2);
        #pragma unroll
        for (int q = 0; q < 4; ++q) {        // C/D: col = lane&15, row = kq*4+q
          const int rr = rb + q;
          if (rr < nd) {
            unsigned short v = f2bf(ae[q] + ao[q]);
            if (rr < CAP) G2L[rr * 16 + lr] = v;
            else          G2g[(size_t)(lbeg + rr) * 16 + lr] = v;
          }
        }
      }
    }
    __syncthreads();   // G2L/CbL handoff to next cell
  }
}

// ---------------- launch ----------------
extern "C" void kernel_launch(void* const* d_in, const int* in_sizes, int n_in,
                              void* d_out, int out_size, void* d_ws, size_t ws_size,
                              hipStream_t stream) {
  const float* X     = (const float*)d_in[0];
  const int*   parent= (const int*)d_in[1];
  const float* Wioux = (const float*)d_in[2];
  const float* bioux = (const float*)d_in[3];
  const float* Wiouh = (const float*)d_in[4];
  const float* biouh = (const float*)d_in[5];
  const float* Wfx   = (const float*)d_in[6];
  const float* bfx   = (const float*)d_in[7];
  const float* Wfh   = (const float*)d_in[8];
  const float* bfh   = (const float*)d_in[9];
  float* out = (float*)d_out;

  char* ws = (char*)d_ws;
  size_t o = 0;
  auto alloc = [&](size_t bytes) { size_t r = o; o += (bytes + 255) & ~(size_t)255; return r; };
  unsigned short* Xb   = (unsigned short*)(ws + alloc((size_t)NN * MD * 2));
  unsigned short* Wpre = (unsigned short*)(ws + alloc((size_t)NOUT * MD * 2));
  unsigned short* XWb  = (unsigned short*)(ws + alloc((size_t)GBLK * NN * 16 * 2));
  unsigned short* G2   = (unsigned short*)(ws + alloc((size_t)GBLK * NN * 16 * 2));
  float* CbB           = (float*)(ws + alloc((size_t)GBLK * NN * 4 * 4));
  unsigned short* Hb   = (unsigned short*)(ws + alloc((size_t)NN * MD * 2));
  float* biasC         = (float*)(ws + alloc((size_t)NOUT * 4));
  int2* meta           = (int2*)(ws + alloc((size_t)NN * 8));
  int* doff            = (int*)(ws + alloc((NN + 4) * 4));
  int* maxd            = (int*)(ws + alloc(256));
  int* flags           = (int*)(ws + alloc((GBLK + 64) * 4));

  // fused: block 0 = prep (dispatched first, overlaps cvt); blocks 1.. = cvt
  {
    const int n4 = (NN * MD + 3072 * MD + 1024 * MD) / 4;
    const int cvt_blocks = (n4 + 1023) / 1024;
    cvt_prep_kernel<<<cvt_blocks + 1, 1024, 0, stream>>>(
        X, Wioux, Wfx, Xb, Wpre,
        parent, meta, doff, maxd, flags,
        bioux, biouh, bfx, bfh, biasC);
  }

  pregemm_kernel<<<(NN / 128) * (NOUT / 128), 256, 0, stream>>>(Xb, Wpre, XWb, biasC);

  RP p;
  p.meta = meta; p.doff = doff; p.maxd = maxd;
  p.XWb = XWb; p.G2 = G2; p.CbB = CbB; p.Hb = Hb;
  p.Wiouh = Wiouh; p.Wfh = Wfh;
  p.out = out; p.flags = flags;
  void* args[] = {&p};
  hipLaunchCooperativeKernel((const void*)recur_kernel, dim3(GBLK), dim3(GTHR), args, 0, stream);

  (void)in_sizes; (void)n_in; (void)out_size; (void)ws_size;
}